// Round 2
// baseline (49.585 us; speedup 1.0000x reference)
//
#include <hip/hip_runtime.h>

namespace {
constexpr int kM = 4, kJ = 2, kI = 3, kL = 2, kW = 9;
constexpr float kInvLn2 = 1.4426950408889634f;

__device__ __forceinline__ float fexp2(float x) { return __builtin_amdgcn_exp2f(x); }

// One fused kernel. Per block (256 batch rows):
//   phase 0: threads 0..11 fold rule params into sdp[80] (log2-scaled quad coeffs)
//            all threads cooperatively stage 18432 B of state into LDS (float4 coalesced)
//   phase 1: per-thread compute from its LDS row (stride-18 reads: 2-way alias, free)
//   phase 2: results via LDS (stride-9, conflict-free) -> coalesced float4 stores
__global__ __launch_bounds__(256) void algelogic_fused(
    const float* __restrict__ state,
    const float* __restrict__ constants,
    const float* __restrict__ gammas,
    const float* __restrict__ W_body,
    const float* __restrict__ b_body,
    const float* __restrict__ W_head,
    const float* __restrict__ b_head,
    float* __restrict__ out) {
  __shared__ float sdata[256 * 18];   // staged state rows
  __shared__ float sout[256 * 9];     // staged output rows
  __shared__ float sdp[80];           // derived params: 8×[A,B0,B1,w0,w1,C00,C01,C10,C11] + D[4][2]

  const int t = threadIdx.x;
  const int blk = blockIdx.x;

  // ---- derived-parameter fold (threads 0..11) ----
  if (t < 8) {
    const int mj = t;                  // m = mj/2, j = mj%2
    const int m = mj >> 1;
    const float g0 = fminf(fmaxf(gammas[mj * kL + 0], 0.f), 1.f);
    const float g1 = fminf(fmaxf(gammas[mj * kL + 1], 0.f), 1.f);
    const float w0 = 1.f - g0, w1 = 1.f - g1;
    const float c0 = constants[mj * kL + 0], c1 = constants[mj * kL + 1];
    const float gavg = 0.5f * (g0 + g1);
    float* p = sdp + mj * 9;
    // quad coeffs of match_score, pre-scaled by 1/ln2 (log2 domain)
    p[0] = (w0 * c0 * c0 + w1 * c1 * c1) * kInvLn2;
    p[1] = -2.f * w0 * c0 * kInvLn2;
    p[2] = -2.f * w1 * c1 * kInvLn2;
    p[3] = w0 * kInvLn2;
    p[4] = w1 * kInvLn2;
    // C[l][lp] = gavg * sum_i Wh[m,l,i] * Wb[m,j,i,lp]   (unscaled)
    for (int l = 0; l < kL; ++l)
      for (int lp = 0; lp < kL; ++lp) {
        float acc = 0.f;
        for (int i = 0; i < kI; ++i)
          acc += W_head[(m * kL + l) * kI + i] * W_body[(mj * kI + i) * kL + lp];
        p[5 + l * kL + lp] = gavg * acc;
      }
  } else if (t < 12) {
    const int m = t - 8;
    for (int l = 0; l < kL; ++l) {
      float d = b_head[m * kL + l];
      for (int j = 0; j < kJ; ++j) {
        const int mj = m * kJ + j;
        const float g0 = fminf(fmaxf(gammas[mj * kL + 0], 0.f), 1.f);
        const float g1 = fminf(fmaxf(gammas[mj * kL + 1], 0.f), 1.f);
        const float gavg = 0.5f * (g0 + g1);
        float acc = 0.f;
        for (int i = 0; i < kI; ++i)
          acc += W_head[(m * kL + l) * kI + i] * b_body[mj * kI + i];
        d += gavg * acc;
      }
      sdp[72 + m * kL + l] = d;
    }
  }

  // ---- coalesced state staging: 1152 float4 per block ----
  {
    const float4* g4 = reinterpret_cast<const float4*>(state + (size_t)blk * (256 * 18));
    float4* l4 = reinterpret_cast<float4*>(sdata);
#pragma unroll
    for (int i = 0; i < 4; ++i) l4[i * 256 + t] = g4[i * 256 + t];
    if (t < 128) l4[1024 + t] = g4[1024 + t];
  }
  __syncthreads();

  // ---- per-thread row from LDS ----
  float s0[kW], s1[kW], q0[kW], q1[kW];
  {
    const float* srow = sdata + t * 18;
#pragma unroll
    for (int w = 0; w < kW; ++w) {
      const float2 v = *reinterpret_cast<const float2*>(srow + 2 * w);
      s0[w] = v.x; s1[w] = v.y;
      q0[w] = v.x * v.x; q1[w] = v.y * v.y;
    }
  }

  float Cs = 0.f, X0 = 0.f, X1 = 0.f, K = 0.f;
#pragma unroll
  for (int m = 0; m < kM; ++m) {
    float mq2 = 0.f;                       // match_quality in log2 units
    float r0 = sdp[72 + m * 2 + 0];
    float r1 = sdp[72 + m * 2 + 1];
#pragma unroll
    for (int j = 0; j < kJ; ++j) {
      const float* p = sdp + (m * kJ + j) * 9;
      const float A = p[0], B0 = p[1], B1 = p[2], w0 = p[3], w1 = p[4];
      float ms[kW];
      float msmin = 3.4e38f;
#pragma unroll
      for (int w = 0; w < kW; ++w) {
        const float v = A + B0 * s0[w] + w0 * q0[w] + B1 * s1[w] + w1 * q1[w];
        ms[w] = v;
        msmin = fminf(msmin, v);
      }
      float psum = 0.f, pb0 = 0.f, pb1 = 0.f, pmq = 0.f;
#pragma unroll
      for (int w = 0; w < kW; ++w) {
        const float e = fexp2(msmin - ms[w]);   // == exp(min-ms) in nat units
        psum += e;
        pb0 += e * s0[w];
        pb1 += e * s1[w];
        pmq += e * ms[w];                       // log2-scaled ms
      }
      const float rinv = __builtin_amdgcn_rcpf(psum);
      const float best0 = pb0 * rinv, best1 = pb1 * rinv;
      mq2 += pmq * rinv;
      r0 += p[5] * best0 + p[6] * best1;
      r1 += p[7] * best0 + p[8] * best1;
    }
    const float conf = fexp2(-mq2);            // == exp(-match_quality)
    Cs += conf;
    X0 += conf * r0;
    X1 += conf * r1;
    K  += conf * (r0 * r0 + r1 * r1);
  }
  const float X02 = 2.f * X0, X12 = 2.f * X1;

  // ---- factored similarity -> LDS (stride 9, conflict-free) ----
  {
    float* orow = sout + t * 9;
#pragma unroll
    for (int w = 0; w < kW; ++w) {
      orow[w] = X02 * s0[w] + X12 * s1[w] - Cs * (q0[w] + q1[w]) - K;
    }
  }
  __syncthreads();

  // ---- coalesced output store: 576 float4 per block ----
  {
    float4* o4 = reinterpret_cast<float4*>(out + (size_t)blk * (256 * 9));
    const float4* so4 = reinterpret_cast<const float4*>(sout);
    o4[t] = so4[t];
    o4[256 + t] = so4[256 + t];
    if (t < 64) o4[512 + t] = so4[512 + t];
  }
}
}  // namespace

extern "C" void kernel_launch(void* const* d_in, const int* in_sizes, int n_in,
                              void* d_out, int out_size, void* d_ws, size_t ws_size,
                              hipStream_t stream) {
  const float* state     = (const float*)d_in[0];
  const float* constants = (const float*)d_in[1];
  const float* gammas    = (const float*)d_in[2];
  const float* W_body    = (const float*)d_in[3];
  const float* b_body    = (const float*)d_in[4];
  const float* W_head    = (const float*)d_in[5];
  const float* b_head    = (const float*)d_in[6];
  float* out = (float*)d_out;

  const int B = in_sizes[0] / (kW * kL);   // 1048576
  hipLaunchKernelGGL(algelogic_fused, dim3(B / 256), dim3(256), 0, stream,
                     state, constants, gammas, W_body, b_body, W_head, b_head, out);
}

// Round 3
// 35.564 us; speedup vs baseline: 1.3942x; 1.3942x over previous
//
#include <hip/hip_runtime.h>

namespace {
constexpr int kM = 4, kJ = 2, kI = 3, kL = 2, kW = 9;
constexpr float kInvLn2 = 1.4426950408889634f;

typedef float v2f __attribute__((ext_vector_type(2)));  // lowers to <2 x float> -> v_pk_*_f32

__device__ __forceinline__ float fexp2(float x) { return __builtin_amdgcn_exp2f(x); }

// Fused kernel. Tiny LDS param fold (80 floats, j-packed), then per-thread
// batch-element compute with J-packed (v2f) arithmetic. Direct global I/O
// (L1 absorbs the 72B-stride pattern — proven round 1 vs round 2).
//
// sdp layout, per m (18 floats at m*18), j-packed pairs:
//   [A, B0, B1, w0, w1, C00, C01, C10, C11] each as {j0,j1}
//   A/B/w are pre-scaled by 1/ln2 (log2 domain); D[m][l] at 72 + m*2 + l.
__global__ __launch_bounds__(256) void algelogic_fused(
    const float* __restrict__ state,
    const float* __restrict__ constants,
    const float* __restrict__ gammas,
    const float* __restrict__ W_body,
    const float* __restrict__ b_body,
    const float* __restrict__ W_head,
    const float* __restrict__ b_head,
    float* __restrict__ out) {
  __shared__ float sdp[80];
  const int t = threadIdx.x;

  if (t < 8) {
    const int mj = t, m = t >> 1, j = t & 1;
    const float g0 = fminf(fmaxf(gammas[mj * kL + 0], 0.f), 1.f);
    const float g1 = fminf(fmaxf(gammas[mj * kL + 1], 0.f), 1.f);
    const float w0 = 1.f - g0, w1 = 1.f - g1;
    const float c0 = constants[mj * kL + 0], c1 = constants[mj * kL + 1];
    const float gavg = 0.5f * (g0 + g1);
    float* base = sdp + m * 18;
    base[0 * 2 + j] = (w0 * c0 * c0 + w1 * c1 * c1) * kInvLn2;  // A
    base[1 * 2 + j] = -2.f * w0 * c0 * kInvLn2;                 // B0
    base[2 * 2 + j] = -2.f * w1 * c1 * kInvLn2;                 // B1
    base[3 * 2 + j] = w0 * kInvLn2;                             // w0
    base[4 * 2 + j] = w1 * kInvLn2;                             // w1
    for (int l = 0; l < kL; ++l)
      for (int lp = 0; lp < kL; ++lp) {
        float acc = 0.f;
        for (int i = 0; i < kI; ++i)
          acc += W_head[(m * kL + l) * kI + i] * W_body[(mj * kI + i) * kL + lp];
        base[(5 + l * kL + lp) * 2 + j] = gavg * acc;           // C[l][lp]
      }
  } else if (t < 12) {
    const int m = t - 8;
    for (int l = 0; l < kL; ++l) {
      float d = b_head[m * kL + l];
      for (int j = 0; j < kJ; ++j) {
        const int mj = m * kJ + j;
        const float g0 = fminf(fmaxf(gammas[mj * kL + 0], 0.f), 1.f);
        const float g1 = fminf(fmaxf(gammas[mj * kL + 1], 0.f), 1.f);
        const float gavg = 0.5f * (g0 + g1);
        float acc = 0.f;
        for (int i = 0; i < kI; ++i)
          acc += W_head[(m * kL + l) * kI + i] * b_body[mj * kI + i];
        d += gavg * acc;
      }
      sdp[72 + m * kL + l] = d;
    }
  }
  __syncthreads();

  const int b = blockIdx.x * 256 + t;
  const float* srow = state + (size_t)b * (kW * kL);

  // sv[w] = (s0, s1) packed over l (as loaded); qv = squares
  v2f sv[kW], qv[kW];
#pragma unroll
  for (int w = 0; w < kW; ++w) {
    const float2 v = *reinterpret_cast<const float2*>(srow + 2 * w);
    v2f s; s.x = v.x; s.y = v.y;
    sv[w] = s;
    qv[w] = s * s;
  }

  float Cs = 0.f, X0 = 0.f, X1 = 0.f, K = 0.f;
#pragma unroll
  for (int m = 0; m < kM; ++m) {
    const v2f* pp = reinterpret_cast<const v2f*>(sdp + m * 18);
    const v2f A = pp[0], B0 = pp[1], B1 = pp[2], w0 = pp[3], w1 = pp[4];

    v2f msP[kW];
    v2f mn = {3.4e38f, 3.4e38f};
#pragma unroll
    for (int w = 0; w < kW; ++w) {
      const float s0w = sv[w].x, s1w = sv[w].y;
      const float q0w = qv[w].x, q1w = qv[w].y;
      v2f v = A + B0 * s0w;     // j-packed quad, 4 pk_fma
      v += w0 * q0w;
      v += B1 * s1w;
      v += w1 * q1w;
      msP[w] = v;
      mn = __builtin_elementwise_min(mn, v);
    }

    v2f psum = {0.f, 0.f}, pb0 = {0.f, 0.f}, pb1 = {0.f, 0.f}, pmq = {0.f, 0.f};
#pragma unroll
    for (int w = 0; w < kW; ++w) {
      const v2f d = mn - msP[w];          // <= 0, log2 units
      v2f e; e.x = fexp2(d.x); e.y = fexp2(d.y);
      psum += e;
      pb0 += e * sv[w].x;
      pb1 += e * sv[w].y;
      pmq += e * msP[w];                  // log2-scaled ms
    }

    v2f rinv;
    rinv.x = __builtin_amdgcn_rcpf(psum.x);
    rinv.y = __builtin_amdgcn_rcpf(psum.y);
    const v2f bb0 = pb0 * rinv, bb1 = pb1 * rinv;
    const v2f mqP = pmq * rinv;
    const float mq2 = mqP.x + mqP.y;      // sum over j (log2 units)
    const float conf = fexp2(-mq2);       // == exp(-match_quality)

    const v2f C00 = pp[5], C01 = pp[6], C10 = pp[7], C11 = pp[8];
    const v2f t0 = C00 * bb0 + C01 * bb1;
    const v2f t1 = C10 * bb0 + C11 * bb1;
    const float r0 = sdp[72 + m * 2 + 0] + t0.x + t0.y;
    const float r1 = sdp[72 + m * 2 + 1] + t1.x + t1.y;

    Cs += conf;
    X0 = fmaf(conf, r0, X0);
    X1 = fmaf(conf, r1, X1);
    K = fmaf(conf, fmaf(r0, r0, r1 * r1), K);
  }

  const float X02 = 2.f * X0, X12 = 2.f * X1;
  float* orow = out + (size_t)b * kW;
#pragma unroll
  for (int w = 0; w < kW; ++w) {
    const float qs = qv[w].x + qv[w].y;
    // out = 2X0*s0 + 2X1*s1 - Cs*(s0^2+s1^2) - K
    orow[w] = fmaf(X02, sv[w].x, fmaf(X12, sv[w].y, fmaf(-Cs, qs, -K)));
  }
}
}  // namespace

extern "C" void kernel_launch(void* const* d_in, const int* in_sizes, int n_in,
                              void* d_out, int out_size, void* d_ws, size_t ws_size,
                              hipStream_t stream) {
  const float* state     = (const float*)d_in[0];
  const float* constants = (const float*)d_in[1];
  const float* gammas    = (const float*)d_in[2];
  const float* W_body    = (const float*)d_in[3];
  const float* b_body    = (const float*)d_in[4];
  const float* W_head    = (const float*)d_in[5];
  const float* b_head    = (const float*)d_in[6];
  float* out = (float*)d_out;

  const int B = in_sizes[0] / (kW * kL);   // 1048576
  hipLaunchKernelGGL(algelogic_fused, dim3(B / 256), dim3(256), 0, stream,
                     state, constants, gammas, W_body, b_body, W_head, b_head, out);
}